// Round 4
// baseline (122.296 us; speedup 1.0000x reference)
//
#include <hip/hip_runtime.h>
#include <hip/hip_bf16.h>

// Problem constants
#define B_   4
#define N_   160
#define D_   64
#define ZI_  64
#define H1_  128
#define H2_  64
#define L_   4
#define LE_  8

typedef __bf16 bf16x8 __attribute__((ext_vector_type(8)));
typedef float  f32x4  __attribute__((ext_vector_type(4)));

// ---------------------------------------------------------------------------
// Stage A (MFMA): grid 40 blocks x 256 threads. Block = 16 consecutive
// (b,i) rows (one M-tile; 160%16==0 so a tile never crosses b). Wave w
// selects the output column-block:
//   w0: ui[row,h]  = ([ne_row | zi_b] @ [Wi1_a; Wi1_z])[h] + bi1[h]   (fp32)
//   w1: vpi[row,h] = bf16( (ne_row @ Wi1_b)[h] )
//   w2: uq[b,l,i,h]= ([ne_row | ze_b] @ [Wl1_a; Wl1_z])[h] + bl1[h]
//                    + (lag_l @ Wl1_l)[h]                              (fp32)
//   w3: vpl[row,h] = bf16( (ne_row @ Wl1_b)[h] )
// MFMA 16x16x32 layouts (HW-verified):
//   A: lane holds A[m = lane&15][k = 8*(lane>>4)+j]
//   B: lane holds B[k = 8*(lane>>4)+j][n = lane&15]
//   C/D: lane holds D[row = 4*(lane>>4)+reg][col = lane&15]
// Unified W1-row formula: wrow = (colb || kt>=2) ? 64+k : k
//   (colb waves read Wx1_b rows 64..127; kt>=2 reads z-rows 128..191).
// ---------------------------------------------------------------------------
__global__ __launch_bounds__(256, 1) void stage_a(
    const float* __restrict__ ne,
    const float* __restrict__ zi,
    const float* __restrict__ ze,
    const float* __restrict__ lag,
    const float* __restrict__ Wi1,
    const float* __restrict__ bi1,
    const float* __restrict__ Wl1,
    const float* __restrict__ bl1,
    float* __restrict__ ui, float* __restrict__ uq,
    __bf16* __restrict__ vpi, __bf16* __restrict__ vpl)
{
    const int mt   = blockIdx.x;           // 0..39
    const int w    = threadIdx.x >> 6;     // column-block 0..3
    const int lane = threadIdx.x & 63;
    const int q = lane >> 4;
    const int c = lane & 15;

    const int r0 = mt * 16;                // global row base (b*N + i)
    const int b  = mt / 10;
    const int i0 = r0 - b * N_;

    const float* W1   = (w < 2) ? Wi1 : Wl1;
    const bool   colb = (w & 1);           // pj/qj waves (K=64 only)
    const float* zv   = (w == 2) ? (ze + b * ZI_) : (zi + b * ZI_);
    const int    nkt  = colb ? 2 : 4;

    // A fragments: kt 0..1 from ne rows, kt 2..3 broadcast z-vector.
    bf16x8 af[4];
#pragma unroll
    for (int kt = 0; kt < 2; ++kt) {
        const float* ap = ne + (r0 + c) * D_ + 32 * kt + 8 * q;
        const f32x4 x0 = *(const f32x4*)ap;
        const f32x4 x1 = *(const f32x4*)(ap + 4);
        bf16x8 t;
#pragma unroll
        for (int j = 0; j < 4; ++j) { t[j] = (__bf16)x0[j]; t[4 + j] = (__bf16)x1[j]; }
        af[kt] = t;
    }
    if (!colb) {
#pragma unroll
        for (int kt = 2; kt < 4; ++kt) {
            const float* ap = zv + 32 * (kt - 2) + 8 * q;
            const f32x4 x0 = *(const f32x4*)ap;
            const f32x4 x1 = *(const f32x4*)(ap + 4);
            bf16x8 t;
#pragma unroll
            for (int j = 0; j < 4; ++j) { t[j] = (__bf16)x0[j]; t[4 + j] = (__bf16)x1[j]; }
            af[kt] = t;
        }
    }

#pragma unroll
    for (int nt = 0; nt < 8; ++nt) {
        const int col = 16 * nt + c;

        // B fragments for this n-tile.
        bf16x8 bfr[4];
#pragma unroll
        for (int kt = 0; kt < 4; ++kt) {
            if (kt >= nkt) break;
            bf16x8 t;
#pragma unroll
            for (int j = 0; j < 8; ++j) {
                const int k = 32 * kt + 8 * q + j;
                const int wrow = (colb || kt >= 2) ? (64 + k) : k;
                t[j] = (__bf16)W1[wrow * H1_ + col];
            }
            bfr[kt] = t;
        }

        // acc init = bias (w0/w2) or 0.
        float binit = 0.f;
        if (w == 0) binit = bi1[col];
        if (w == 2) binit = bl1[col];
        f32x4 acc = {binit, binit, binit, binit};

#pragma unroll
        for (int kt = 0; kt < 4; ++kt) {
            if (kt >= nkt) break;
            acc = __builtin_amdgcn_mfma_f32_16x16x32_bf16(af[kt], bfr[kt], acc, 0, 0, 0);
        }

        if (w == 0) {
#pragma unroll
            for (int rr = 0; rr < 4; ++rr)
                ui[(r0 + 4 * q + rr) * H1_ + col] = acc[rr];
        } else if (w == 1) {
#pragma unroll
            for (int rr = 0; rr < 4; ++rr)
                vpi[(r0 + 4 * q + rr) * H1_ + col] = (__bf16)acc[rr];
        } else if (w == 3) {
#pragma unroll
            for (int rr = 0; rr < 4; ++rr)
                vpl[(r0 + 4 * q + rr) * H1_ + col] = (__bf16)acc[rr];
        } else {
            // lag contribution for this col (fp32), then 4 lag copies.
            float lw[4] = {0.f, 0.f, 0.f, 0.f};
#pragma unroll
            for (int e = 0; e < LE_; ++e) {
                const float we = Wl1[(2 * D_ + ZI_ + e) * H1_ + col];
#pragma unroll
                for (int l = 0; l < L_; ++l) lw[l] += lag[l * LE_ + e] * we;
            }
#pragma unroll
            for (int l = 0; l < L_; ++l)
#pragma unroll
                for (int rr = 0; rr < 4; ++rr)
                    uq[((b * L_ + l) * N_ + i0 + 4 * q + rr) * H1_ + col] = acc[rr] + lw[l];
        }
    }
}

// ---------------------------------------------------------------------------
// Stage B: fused pairwise MLP via MFMA, j-panel staged in LDS per block.
// Block = 4 waves = 4 consecutive row-ids, always same batch/branch.
// Panel bf16 160x128 in LDS, XOR swizzle granule' = g ^ (row&7) -> conflict-
// free; 40960 B -> 4 blocks/CU. b2 folded into MFMA acc init. jt unroll 2.
// ---------------------------------------------------------------------------
__global__ __launch_bounds__(256) void stage_b(
    const float* __restrict__ ui, const float* __restrict__ uq,
    const __bf16* __restrict__ vpi, const __bf16* __restrict__ vpl,
    const float* __restrict__ Wi2, const float* __restrict__ bi2,
    const float* __restrict__ Wi3, const float* __restrict__ bi3,
    const float* __restrict__ Wl2, const float* __restrict__ bl2,
    const float* __restrict__ Wl3, const float* __restrict__ bl3,
    float* __restrict__ out)
{
    __shared__ __bf16 panel[N_ * H1_];   // 40960 B, swizzled

    const int t    = threadIdx.x;
    const int wid  = t >> 6;
    const int lane = t & 63;
    const int q = lane >> 4;
    const int c = lane & 15;

    const int blk  = blockIdx.x;         // 0..799
    const int wave = blk * 4 + wid;

    const __bf16* psrc;
    if (blk < 160) psrc = vpi + (blk / 40) * (N_ * H1_);
    else           psrc = vpl + ((blk - 160) / 160) * (N_ * H1_);

    const float* ubase;
    const float *W2, *b2, *w3;
    float b3f;
    long  obase;
    int   i;
    if (wave < B_ * N_) {                      // intra: W_t
        i = wave % N_;
        ubase = ui + wave * H1_;
        W2 = Wi2; b2 = bi2; w3 = Wi3; b3f = bi3[0];
        obase = (long)wave * N_;
    } else {                                   // inter: A_lags_t
        const int w2i = wave - B_ * N_;
        i = w2i % N_;
        ubase = uq + w2i * H1_;
        W2 = Wl2; b2 = bl2; w3 = Wl3; b3f = bl3[0];
        obase = (long)B_ * N_ * N_ + (long)w2i * N_;
    }

    // 1) Panel global loads first (coalesced 16B per thread x 10).
    bf16x8 stg[10];
#pragma unroll
    for (int it = 0; it < 10; ++it)
        stg[it] = *(const bf16x8*)(psrc + 2048 * it + 8 * t);

    // 2) Register loads overlapping the panel loads.
    bf16x8 bfr[4][4];
#pragma unroll
    for (int kt = 0; kt < 4; ++kt)
#pragma unroll
        for (int ct = 0; ct < 4; ++ct) {
            bf16x8 tt;
#pragma unroll
            for (int j = 0; j < 8; ++j)
                tt[j] = (__bf16)W2[(32 * kt + 8 * q + j) * H2_ + 16 * ct + c];
            bfr[kt][ct] = tt;
        }

    f32x4 u0[4], u1[4];
#pragma unroll
    for (int kt = 0; kt < 4; ++kt) {
        const float* up = ubase + 32 * kt + 8 * q;
        u0[kt] = *(const f32x4*)(up);
        u1[kt] = *(const f32x4*)(up + 4);
    }

    float b2c[4], w3c[4];
#pragma unroll
    for (int ct = 0; ct < 4; ++ct) {
        b2c[ct] = b2[16 * ct + c];
        w3c[ct] = w3[16 * ct + c];
    }

    // 3) Swizzled LDS write.
    {
        const int gsw = (t & 15) ^ ((t >> 4) & 7);
        const int rowbase = (t >> 4) * H1_ + gsw * 8;
#pragma unroll
        for (int it = 0; it < 10; ++it)
            *(bf16x8*)(panel + 16 * it * H1_ + rowbase) = stg[it];
    }
    __syncthreads();

    // 4) Tile loop, two tiles in flight.
#pragma unroll 2
    for (int jt = 0; jt < 10; ++jt) {
        const __bf16* prow = panel + (16 * jt + c) * H1_;
        f32x4 acc[4];
#pragma unroll
        for (int ct = 0; ct < 4; ++ct)
            acc[ct] = (f32x4){b2c[ct], b2c[ct], b2c[ct], b2c[ct]};

#pragma unroll
        for (int kt = 0; kt < 4; ++kt) {
            const bf16x8 vb = *(const bf16x8*)(prow + (((4 * kt + q) ^ (c & 7)) << 3));
            bf16x8 a;
#pragma unroll
            for (int j = 0; j < 4; ++j) {
                a[j]     = (__bf16)fmaxf(u0[kt][j] + (float)vb[j],     0.f);
                a[4 + j] = (__bf16)fmaxf(u1[kt][j] + (float)vb[4 + j], 0.f);
            }
#pragma unroll
            for (int ct = 0; ct < 4; ++ct)
                acc[ct] = __builtin_amdgcn_mfma_f32_16x16x32_bf16(
                    a, bfr[kt][ct], acc[ct], 0, 0, 0);
        }

        float logit[4];
#pragma unroll
        for (int r = 0; r < 4; ++r) {
            float p = 0.f;
#pragma unroll
            for (int ct = 0; ct < 4; ++ct) {
                const float h2 = fmaxf(acc[ct][r], 0.f);   // b2 already in acc
                p += h2 * w3c[ct];
            }
            p += __shfl_xor(p, 1);
            p += __shfl_xor(p, 2);
            p += __shfl_xor(p, 4);
            p += __shfl_xor(p, 8);
            logit[r] = p;
        }

        if (c < 4) {
            const int j = 16 * jt + 4 * q + c;
            const float lg = logit[c] + b3f;
            const float s = (j == i) ? 0.f : 1.f / (1.f + __expf(-lg));
            out[obase + j] = s;
        }
    }
}

// ---------------------------------------------------------------------------
extern "C" void kernel_launch(void* const* d_in, const int* in_sizes, int n_in,
                              void* d_out, int out_size, void* d_ws, size_t ws_size,
                              hipStream_t stream) {
    const float* ne  = (const float*)d_in[0];
    const float* zi  = (const float*)d_in[1];
    const float* ze  = (const float*)d_in[2];
    const float* lag = (const float*)d_in[3];
    const float* Wi1 = (const float*)d_in[4];
    const float* bi1 = (const float*)d_in[5];
    const float* Wi2 = (const float*)d_in[6];
    const float* bi2 = (const float*)d_in[7];
    const float* Wi3 = (const float*)d_in[8];
    const float* bi3 = (const float*)d_in[9];
    const float* Wl1 = (const float*)d_in[10];
    const float* bl1 = (const float*)d_in[11];
    const float* Wl2 = (const float*)d_in[12];
    const float* bl2 = (const float*)d_in[13];
    const float* Wl3 = (const float*)d_in[14];
    const float* bl3 = (const float*)d_in[15];

    float*  ws  = (float*)d_ws;
    float*  ui  = ws;                          // 640*128 fp32
    float*  uqw = ws + 81920;                  // 2560*128 fp32
    __bf16* vpi = (__bf16*)(ws + 409600);      // 640*128 bf16
    __bf16* vpl = vpi + 81920;                 // 640*128 bf16

    stage_a<<<40, 256, 0, stream>>>(ne, zi, ze, lag, Wi1, bi1, Wl1, bl1,
                                    ui, uqw, vpi, vpl);

    stage_b<<<(B_ * N_ + B_ * L_ * N_) / 4, 256, 0, stream>>>(
        ui, uqw, vpi, vpl,
        Wi2, bi2, Wi3, bi3, Wl2, bl2, Wl3, bl3,
        (float*)d_out);
}

// Round 5
// 113.828 us; speedup vs baseline: 1.0744x; 1.0744x over previous
//
#include <hip/hip_runtime.h>
#include <hip/hip_bf16.h>

// Problem constants
#define B_   4
#define N_   160
#define D_   64
#define ZI_  64
#define H1_  128
#define H2_  64
#define L_   4
#define LE_  8

typedef __bf16 bf16x8 __attribute__((ext_vector_type(8)));
typedef float  f32x4  __attribute__((ext_vector_type(4)));

// ---------------------------------------------------------------------------
// Stage A: per-(b,i) precompute (scalar version — measured ~3 µs).
//   ui[b,i,h]   = ne[b,i]@Wi1[:64] + z_intra[b]@Wi1[128:192] + bi1      (fp32)
//   uq[b,l,i,h] = ne[b,i]@Wl1[:64] + z_inter[b]@Wl1[128:192] + lag[l]@Wl1_l + bl1
//   vpi[b,j,h]  = bf16( ne[b,j]@Wi1[64:128] )
//   vpl[b,j,h]  = bf16( ne[b,j]@Wl1[64:128] )
// Blocks 0/1 additionally emit Wi2/Wl2 as bf16 MFMA-B-fragment-ordered
// arrays (16 KB each) so stage_b's setup is 16 coalesced 16B loads instead
// of 128 scalar loads (VGPR_Count=84 in R2 proved the compiler was
// re-gathering W2 fragments every jt iteration — the 29 µs mystery).
// grid = B*N blocks, 128 threads (h)
// ---------------------------------------------------------------------------
__global__ __launch_bounds__(128) void stage_a(
    const float* __restrict__ ne,
    const float* __restrict__ zi,
    const float* __restrict__ ze,
    const float* __restrict__ lag,
    const float* __restrict__ Wi1,
    const float* __restrict__ bi1,
    const float* __restrict__ Wl1,
    const float* __restrict__ bl1,
    const float* __restrict__ Wi2,
    const float* __restrict__ Wl2,
    float* __restrict__ ui, float* __restrict__ uq,
    __bf16* __restrict__ vpi, __bf16* __restrict__ vpl,
    __bf16* __restrict__ W2fi, __bf16* __restrict__ W2fl)
{
    const int bi = blockIdx.x;       // b*N + i
    const int b  = bi / N_;
    const int h  = threadIdx.x;      // 0..127

    const float* nerow = ne + bi * D_;

    float pi_ = 0.f, pj_ = 0.f, qi_ = 0.f, qj_ = 0.f;
#pragma unroll 16
    for (int d = 0; d < D_; ++d) {
        const float a = nerow[d];
        pi_ += a * Wi1[d * H1_ + h];
        pj_ += a * Wi1[(D_ + d) * H1_ + h];
        qi_ += a * Wl1[d * H1_ + h];
        qj_ += a * Wl1[(D_ + d) * H1_ + h];
    }
    float pz = 0.f, qz = 0.f;
#pragma unroll 16
    for (int z = 0; z < ZI_; ++z) {
        pz += zi[b * ZI_ + z] * Wi1[(2 * D_ + z) * H1_ + h];
        qz += ze[b * ZI_ + z] * Wl1[(2 * D_ + z) * H1_ + h];
    }

    ui[bi * H1_ + h]  = pi_ + pz + bi1[h];
    vpi[bi * H1_ + h] = (__bf16)pj_;
    vpl[bi * H1_ + h] = (__bf16)qj_;

    const float qbase = qi_ + qz + bl1[h];
#pragma unroll
    for (int l = 0; l < L_; ++l) {
        float ql = 0.f;
#pragma unroll
        for (int e = 0; e < LE_; ++e)
            ql += lag[l * LE_ + e] * Wl1[(2 * D_ + ZI_ + e) * H1_ + h];
        uq[((b * L_ + l) * N_ + (bi % N_)) * H1_ + h] = qbase + ql;
    }

    // W2 -> bf16 fragment layout. Chunk fc = (kt*4+ct)*64 + lane holds the
    // 8 values lane needs for fragment (kt,ct):
    //   W2[(32*kt + 8*q + j)*H2 + 16*ct + c], q=(lane>>4), c=lane&15.
    if (bi < 2) {
        const float* Wsrc = (bi == 0) ? Wi2 : Wl2;
        __bf16* Wdst = (bi == 0) ? W2fi : W2fl;
#pragma unroll
        for (int r = 0; r < 8; ++r) {
            const int fc = h + 128 * r;
            const int kt = fc >> 8, ct = (fc >> 6) & 3;
            const int q = (fc >> 4) & 3, c = fc & 15;
            bf16x8 t;
#pragma unroll
            for (int j = 0; j < 8; ++j)
                t[j] = (__bf16)Wsrc[(32 * kt + 8 * q + j) * H2_ + 16 * ct + c];
            *(bf16x8*)(Wdst + fc * 8) = t;
        }
    }
}

// ---------------------------------------------------------------------------
// Stage B: fused pairwise MLP via MFMA, j-panel staged in LDS per block.
// Block = 4 waves = 4 consecutive row-ids, same batch/branch. Panel bf16
// 160x128 in LDS, XOR swizzle g' = g ^ (row&7) -> conflict-free; 40960 B.
// __launch_bounds__(256,2): VGPR cap 256 so W2 fragments (64 VGPRs) and u
// slices (32 VGPRs) stay register-resident across the jt loop (at the
// default-chosen 84 VGPRs they provably could not).
// MFMA 16x16x32 layouts (HW-verified):
//   A: lane holds A[m=lane&15][k=8*(lane>>4)+j]
//   B: lane holds B[k=8*(lane>>4)+j][n=lane&15]
//   C/D: lane holds D[row=4*(lane>>4)+reg][col=lane&15]
// ---------------------------------------------------------------------------
__global__ __launch_bounds__(256, 2) void stage_b(
    const float* __restrict__ ui, const float* __restrict__ uq,
    const __bf16* __restrict__ vpi, const __bf16* __restrict__ vpl,
    const __bf16* __restrict__ W2fi, const __bf16* __restrict__ W2fl,
    const float* __restrict__ bi2, const float* __restrict__ bi3,
    const float* __restrict__ bl2, const float* __restrict__ bl3,
    const float* __restrict__ Wi3, const float* __restrict__ Wl3,
    float* __restrict__ out)
{
    __shared__ __bf16 panel[N_ * H1_];   // 40960 B, swizzled

    const int t    = threadIdx.x;
    const int wid  = t >> 6;
    const int lane = t & 63;
    const int q = lane >> 4;
    const int c = lane & 15;

    const int blk  = blockIdx.x;         // 0..799
    const int wave = blk * 4 + wid;

    // Block-uniform panel + W2-fragment source.
    const __bf16 *psrc, *Wf;
    if (blk < 160) { psrc = vpi + (blk / 40) * (N_ * H1_);          Wf = W2fi; }
    else           { psrc = vpl + ((blk - 160) / 160) * (N_ * H1_); Wf = W2fl; }

    // Wave-specific row params.
    const float* ubase;
    const float *b2, *w3;
    float b3f;
    long  obase;
    int   i;
    if (wave < B_ * N_) {                      // intra: W_t
        i = wave % N_;
        ubase = ui + wave * H1_;
        b2 = bi2; w3 = Wi3; b3f = bi3[0];
        obase = (long)wave * N_;
    } else {                                   // inter: A_lags_t
        const int w2i = wave - B_ * N_;
        i = w2i % N_;
        ubase = uq + w2i * H1_;
        b2 = bl2; w3 = Wl3; b3f = bl3[0];
        obase = (long)B_ * N_ * N_ + (long)w2i * N_;
    }

    // 1) Panel global loads first (coalesced 16B per thread x 10).
    bf16x8 stg[10];
#pragma unroll
    for (int it = 0; it < 10; ++it)
        stg[it] = *(const bf16x8*)(psrc + 2048 * it + 8 * t);

    // 2) W2 fragments: 16 coalesced 16B loads, register-resident.
    bf16x8 bfr[4][4];
#pragma unroll
    for (int kt = 0; kt < 4; ++kt)
#pragma unroll
        for (int ct = 0; ct < 4; ++ct)
            bfr[kt][ct] = *(const bf16x8*)(Wf + ((kt * 4 + ct) * 64 + lane) * 8);

    f32x4 u0[4], u1[4];
#pragma unroll
    for (int kt = 0; kt < 4; ++kt) {
        const float* up = ubase + 32 * kt + 8 * q;
        u0[kt] = *(const f32x4*)(up);
        u1[kt] = *(const f32x4*)(up + 4);
    }

    float b2c[4], w3c[4];
#pragma unroll
    for (int ct = 0; ct < 4; ++ct) {
        b2c[ct] = b2[16 * ct + c];
        w3c[ct] = w3[16 * ct + c];
    }

    // 3) Swizzled LDS write.
    {
        const int gsw = (t & 15) ^ ((t >> 4) & 7);
        const int rowbase = (t >> 4) * H1_ + gsw * 8;
#pragma unroll
        for (int it = 0; it < 10; ++it)
            *(bf16x8*)(panel + 16 * it * H1_ + rowbase) = stg[it];
    }
    __syncthreads();

    // 4) Tile loop: LDS + registers only.
    for (int jt = 0; jt < 10; ++jt) {
        const __bf16* prow = panel + (16 * jt + c) * H1_;
        f32x4 acc[4];
#pragma unroll
        for (int ct = 0; ct < 4; ++ct)
            acc[ct] = (f32x4){b2c[ct], b2c[ct], b2c[ct], b2c[ct]};

#pragma unroll
        for (int kt = 0; kt < 4; ++kt) {
            const bf16x8 vb = *(const bf16x8*)(prow + (((4 * kt + q) ^ (c & 7)) << 3));
            bf16x8 a;
#pragma unroll
            for (int j = 0; j < 4; ++j) {
                a[j]     = (__bf16)fmaxf(u0[kt][j] + (float)vb[j],     0.f);
                a[4 + j] = (__bf16)fmaxf(u1[kt][j] + (float)vb[4 + j], 0.f);
            }
#pragma unroll
            for (int ct = 0; ct < 4; ++ct)
                acc[ct] = __builtin_amdgcn_mfma_f32_16x16x32_bf16(
                    a, bfr[kt][ct], acc[ct], 0, 0, 0);
        }

        float logit[4];
#pragma unroll
        for (int r = 0; r < 4; ++r) {
            float p = 0.f;
#pragma unroll
            for (int ct = 0; ct < 4; ++ct) {
                const float h2 = fmaxf(acc[ct][r], 0.f);   // b2 already in acc
                p += h2 * w3c[ct];
            }
            p += __shfl_xor(p, 1);
            p += __shfl_xor(p, 2);
            p += __shfl_xor(p, 4);
            p += __shfl_xor(p, 8);
            logit[r] = p;
        }

        if (c < 4) {
            const int j = 16 * jt + 4 * q + c;
            const float lg = logit[c] + b3f;
            const float s = (j == i) ? 0.f : 1.f / (1.f + __expf(-lg));
            out[obase + j] = s;
        }
    }
}

// ---------------------------------------------------------------------------
extern "C" void kernel_launch(void* const* d_in, const int* in_sizes, int n_in,
                              void* d_out, int out_size, void* d_ws, size_t ws_size,
                              hipStream_t stream) {
    const float* ne  = (const float*)d_in[0];
    const float* zi  = (const float*)d_in[1];
    const float* ze  = (const float*)d_in[2];
    const float* lag = (const float*)d_in[3];
    const float* Wi1 = (const float*)d_in[4];
    const float* bi1 = (const float*)d_in[5];
    const float* Wi2 = (const float*)d_in[6];
    const float* bi2 = (const float*)d_in[7];
    const float* Wi3 = (const float*)d_in[8];
    const float* bi3 = (const float*)d_in[9];
    const float* Wl1 = (const float*)d_in[10];
    const float* bl1 = (const float*)d_in[11];
    const float* Wl2 = (const float*)d_in[12];
    const float* bl2 = (const float*)d_in[13];
    const float* Wl3 = (const float*)d_in[14];
    const float* bl3 = (const float*)d_in[15];

    float*  ws   = (float*)d_ws;
    float*  ui   = ws;                         // 640*128 fp32
    float*  uqw  = ws + 81920;                 // 2560*128 fp32
    __bf16* vpi  = (__bf16*)(ws + 409600);     // 640*128 bf16
    __bf16* vpl  = vpi + 81920;                // 640*128 bf16
    __bf16* W2fi = (__bf16*)(ws + 491520);     // 8192 bf16 (fragment order)
    __bf16* W2fl = W2fi + 8192;                // 8192 bf16

    stage_a<<<B_ * N_, 128, 0, stream>>>(ne, zi, ze, lag, Wi1, bi1, Wl1, bl1,
                                         Wi2, Wl2, ui, uqw, vpi, vpl, W2fi, W2fl);

    stage_b<<<(B_ * N_ + B_ * L_ * N_) / 4, 256, 0, stream>>>(
        ui, uqw, vpi, vpl, W2fi, W2fl,
        bi2, bi3, bl2, bl3, Wi3, Wl3,
        (float*)d_out);
}